// Round 4
// baseline (354.541 us; speedup 1.0000x reference)
//
#include <hip/hip_runtime.h>
#include <stdint.h>

typedef float f32x4 __attribute__((ext_vector_type(4)));
typedef short s16x8 __attribute__((ext_vector_type(8)));
typedef short s16x4 __attribute__((ext_vector_type(4)));

__device__ __forceinline__ unsigned short f2bf(float f) {
    uint32_t u = __float_as_uint(f);
    u += 0x7FFFu + ((u >> 16) & 1u);   // round-to-nearest-even
    return (unsigned short)(u >> 16);
}

// ---------- prep: normalize mem rows, emit MFMA-fragment-packed bf16 ----------
// packed tile (ct,kb): cols [ct*16..+15] x k [kb*32..+31] as 512 shorts at
// ((ct*(C/32)+kb)*512); short lane*8+j = B[col=ct*16+(lane&15)][k=kb*32+(lane>>4)*8+j]
template<int C>
__device__ __forceinline__ void prep_body(const float* __restrict__ mp,
                                          short* __restrict__ nmp,
                                          int ct, short* stage) {
    const int tid = threadIdx.x;       // 256 threads
    const int row = tid >> 4;          // 0..15 (B column)
    const int c4  = tid & 15;
    constexpr int IT = C / 64;
    const float4* src = (const float4*)(mp + (size_t)(ct * 16 + row) * C);
    float4 vals[IT];
    float ss = 0.f;
#pragma unroll
    for (int i = 0; i < IT; ++i) {
        float4 v = src[c4 + 16 * i];
        vals[i] = v;
        ss += v.x * v.x + v.y * v.y + v.z * v.z + v.w * v.w;
    }
#pragma unroll
    for (int m = 1; m < 16; m <<= 1) ss += __shfl_xor(ss, m);
    const float inv = 1.f / fmaxf(sqrtf(ss), 1e-12f);
#pragma unroll
    for (int i = 0; i < IT; ++i) {
        float4 v = vals[i];
        s16x4 o;
        o[0] = (short)f2bf(v.x * inv);
        o[1] = (short)f2bf(v.y * inv);
        o[2] = (short)f2bf(v.z * inv);
        o[3] = (short)f2bf(v.w * inv);
        *(s16x4*)&stage[row * C + (c4 + 16 * i) * 4] = o;
    }
    __syncthreads();
    const int lane = tid & 63;
    const int wv = tid >> 6;
    constexpr int NKB = C / 32;
#pragma unroll
    for (int j = 0; j < NKB / 4; ++j) {
        const int kb = j * 4 + wv;
        const s16x8 v = *(const s16x8*)&stage[(lane & 15) * C + kb * 32 + (lane >> 4) * 8];
        *(s16x8*)&nmp[((size_t)ct * NKB + kb) * 512 + lane * 8] = v;
    }
}

__global__ __launch_bounds__(256) void prep_all(const float* m0, short* n0,
                                                const float* m1, short* n1,
                                                const float* m2, short* n2) {
    __shared__ short stage[16 * 1024];
    const int bid = blockIdx.x;
    if (bid < 64) prep_body<256>(m0, n0, bid, stage);
    else if (bid < 128) prep_body<512>(m1, n1, bid - 64, stage);
    else prep_body<1024>(m2, n2, bid - 128, stage);
}

// ---------- fused unit body: pipelined KC=64 chunks, double-buffered LDS ----------
template<int C>
__device__ __forceinline__ void fused_body(const float* __restrict__ feat,
                                           const float* __restrict__ memv,
                                           const short* __restrict__ nm,
                                           float* __restrict__ out_cat,
                                           float* __restrict__ out_w,
                                           int tile, short* A_s, float (*red)[32],
                                           float* invn, int* rowflag, int* anyflag) {
    constexpr int KC = 64;                  // K chunk: LDS tile 32x64 bf16 = 4 KB
    constexpr int NCH = C / KC;             // 4 / 8 / 16
    constexpr int NKB = C / 32;
    const int tid = threadIdx.x;
    const int wave = tid >> 6;
    const int lane = tid & 63;
    const int g = lane >> 4;
    const int ml = lane & 15;
    const int row0 = tile * 32;
    const int prow = tid >> 4;              // fill row 0..31 (16 consecutive lanes/row)
    const int pc4 = tid & 15;               // float4 index within 64-float chunk row
    const int swzm = ml & 7;

    if (tid == 0) *anyflag = 0;

    f32x4 acc[2][8];
#pragma unroll
    for (int rt = 0; rt < 2; ++rt)
#pragma unroll
        for (int t = 0; t < 8; ++t)
            acc[rt][t] = (f32x4){0.f, 0.f, 0.f, 0.f};

    const float4* srcB = (const float4*)(feat + (size_t)(row0 + prow) * C);
    float4* dstfB = (float4*)(out_cat + (size_t)(row0 + prow) * (2 * C) + C);
    float4* dstzB = (float4*)(out_cat + (size_t)(row0 + prow) * (2 * C));
    const float4 z4 = {0.f, 0.f, 0.f, 0.f};
    const int ldsWr = prow * 64 + (((pc4 >> 1) ^ (prow & 7)) * 8) + (pc4 & 1) * 4;

    float ss = 0.f;
    float4 cur = srcB[pc4];                 // prologue: chunk 0

#pragma unroll
    for (int ck = 0; ck < NCH; ++ck) {
        // (a) prefetch next chunk (hidden under this chunk's GEMM)
        float4 nxt;
        if (ck + 1 < NCH) nxt = srcB[(ck + 1) * 16 + pc4];
        // (b) process cur: f-copy, mf zeros, sumsq, bf16 -> swizzled LDS buf[ck&1]
        dstfB[ck * 16 + pc4] = cur;
        dstzB[ck * 16 + pc4] = z4;
        ss += cur.x * cur.x + cur.y * cur.y + cur.z * cur.z + cur.w * cur.w;
        s16x4 o;
        o[0] = (short)f2bf(cur.x);
        o[1] = (short)f2bf(cur.y);
        o[2] = (short)f2bf(cur.z);
        o[3] = (short)f2bf(cur.w);
        *(s16x4*)&A_s[(ck & 1) * 2048 + ldsWr] = o;
        // (c) barrier: drain LDS only — global loads/stores stay in flight
        asm volatile("s_waitcnt lgkmcnt(0)" ::: "memory");
        __builtin_amdgcn_s_barrier();
        asm volatile("" ::: "memory");
        // (d) GEMM this chunk: A from LDS buf[ck&1], packed B from L2/L3
        const short* As = &A_s[(ck & 1) * 2048];
#pragma unroll
        for (int ks = 0; ks < 2; ++ks) {
            const int kb = ck * 2 + ks;
            const s16x8 a0 = *(const s16x8*)&As[ml * 64 + ((((ks << 2) | g) ^ swzm) * 8)];
            const s16x8 a1 = *(const s16x8*)&As[(16 + ml) * 64 + ((((ks << 2) | g) ^ swzm) * 8)];
            const short* nb = nm + ((size_t)(wave * 8) * NKB + kb) * 512 + lane * 8;
#pragma unroll
            for (int t = 0; t < 8; ++t) {
                const s16x8 b = *(const s16x8*)(nb + (size_t)t * NKB * 512);
                acc[0][t] = __builtin_amdgcn_mfma_f32_16x16x32_bf16(a0, b, acc[0][t], 0, 0, 0);
                acc[1][t] = __builtin_amdgcn_mfma_f32_16x16x32_bf16(a1, b, acc[1][t], 0, 0, 0);
            }
        }
        cur = nxt;
    }

    // ---- invn (norm applied post-GEMM: S = R * invn_row) ----
#pragma unroll
    for (int m = 1; m < 16; m <<= 1) ss += __shfl_xor(ss, m);
    if (pc4 == 0) invn[prow] = 1.f / fmaxf(sqrtf(ss), 1e-12f);
    __syncthreads();

    // C/D layout: col = ml, row = 16*rt + 4*g + i
    float Tt[2][4], IL[2][4];

    // ---- exp (no max-sub: |S| <= 1) + row sum ----
#pragma unroll
    for (int rt = 0; rt < 2; ++rt)
#pragma unroll
        for (int i = 0; i < 4; ++i) {
            const float inv = invn[rt * 16 + g * 4 + i];
            float s = 0.f;
#pragma unroll
            for (int t = 0; t < 8; ++t) {
                const float e = __expf(acc[rt][t][i] * inv);
                acc[rt][t][i] = e;
                s += e;
            }
#pragma unroll
            for (int msk = 1; msk < 16; msk <<= 1) s += __shfl_xor(s, msk);
            if (ml == 0) red[wave][rt * 16 + g * 4 + i] = s;
        }
    __syncthreads();
#pragma unroll
    for (int rt = 0; rt < 2; ++rt)
#pragma unroll
        for (int i = 0; i < 4; ++i) {
            const int row = rt * 16 + g * 4 + i;
            float s = red[0][row];
#pragma unroll
            for (int ww = 1; ww < 8; ++ww) s += red[ww][row];
            Tt[rt][i] = s;
        }

    // ---- softmax weight, hard-shrink, row L1 (disjoint red half: no barrier) ----
#pragma unroll
    for (int rt = 0; rt < 2; ++rt)
#pragma unroll
        for (int i = 0; i < 4; ++i) {
            const float tinv = 1.f / Tt[rt][i];
            float l1 = 0.f;
#pragma unroll
            for (int t = 0; t < 8; ++t) {
                const float w = acc[rt][t][i] * tinv;
                const float d = w - 0.0025f;
                const float v = (d > 0.f) ? (d * w / (d + 1e-12f)) : 0.f;
                acc[rt][t][i] = v;
                l1 += v;
            }
#pragma unroll
            for (int msk = 1; msk < 16; msk <<= 1) l1 += __shfl_xor(l1, msk);
            if (ml == 0) red[8 + wave][rt * 16 + g * 4 + i] = l1;
        }
    __syncthreads();
#pragma unroll
    for (int rt = 0; rt < 2; ++rt)
#pragma unroll
        for (int i = 0; i < 4; ++i) {
            const int row = rt * 16 + g * 4 + i;
            float l1 = red[8][row];
#pragma unroll
            for (int ww = 1; ww < 8; ++ww) l1 += red[8 + ww][row];
            IL[rt][i] = 1.f / fmaxf(l1, 1e-12f);
            if (wave == 0 && ml == 0) {
                rowflag[row] = (l1 > 0.f) ? 1 : 0;
                if (l1 > 0.f) *anyflag = 1;
            }
        }

    // ---- store W ----
#pragma unroll
    for (int rt = 0; rt < 2; ++rt)
#pragma unroll
        for (int t = 0; t < 8; ++t) {
            const int col = wave * 128 + t * 16 + ml;
#pragma unroll
            for (int i = 0; i < 4; ++i) {
                out_w[(size_t)(row0 + rt * 16 + g * 4 + i) * 1024 + col] =
                    acc[rt][t][i] * IL[rt][i];
            }
        }
    __threadfence_block();
    __syncthreads();

    // ---- mf fixup: only rows surviving the shrink (zeros already written) ----
    if (*anyflag != 0) {
        constexpr int CC = C / 64;
#pragma unroll
        for (int rr = 0; rr < 4; ++rr) {
            const int row = wave * 4 + rr;
            if (!rowflag[row]) continue;
            float* dst = out_cat + (size_t)(row0 + row) * (2 * C);
            float mfacc[CC];
#pragma unroll
            for (int cc = 0; cc < CC; ++cc) mfacc[cc] = 0.f;
            const float* wrow = out_w + (size_t)(row0 + row) * 1024;
            for (int jb = 0; jb < 1024; jb += 64) {
                const float wv = wrow[jb + lane];
                unsigned long long msk = __ballot(wv != 0.f);
                while (msk) {
                    const int j = __builtin_ctzll(msk);
                    msk &= msk - 1;
                    const float val = __shfl(wv, j);
                    const float* mrow = memv + (size_t)(jb + j) * C;
#pragma unroll
                    for (int cc = 0; cc < CC; ++cc)
                        mfacc[cc] += val * mrow[cc * 64 + lane];
                }
            }
#pragma unroll
            for (int cc = 0; cc < CC; ++cc) dst[cc * 64 + lane] = mfacc[cc];
        }
    }
}

// ---------- mega kernel: all three units, round-robin interleave ----------
__global__ __launch_bounds__(512, 4) void fused_all(
        const float* f0, const float* m0, const short* n0, float* o0, float* w0,
        const float* f1, const float* m1, const short* n1, float* o1, float* w1,
        const float* f2, const float* m2, const short* n2, float* o2, float* w2) {
    __shared__ short A_s[2 * 32 * 64];      // double-buffered 4 KB tiles
    __shared__ float red[16][32];
    __shared__ float invn[32];
    __shared__ int rowflag[32];
    __shared__ int anyflag;

    const int bid = blockIdx.x;
    const int unit = bid % 3;
    const int tile = bid / 3;
    if (unit == 2)
        fused_body<1024>(f2, m2, n2, o2, w2, tile, A_s, red, invn, rowflag, &anyflag);
    else if (unit == 1)
        fused_body<512>(f1, m1, n1, o1, w1, tile, A_s, red, invn, rowflag, &anyflag);
    else
        fused_body<256>(f0, m0, n0, o0, w0, tile, A_s, red, invn, rowflag, &anyflag);
}

extern "C" void kernel_launch(void* const* d_in, const int* in_sizes, int n_in,
                              void* d_out, int out_size, void* d_ws, size_t ws_size,
                              hipStream_t stream) {
    const float* feat[3] = {nullptr, nullptr, nullptr};
    const float* memp[3] = {nullptr, nullptr, nullptr};
    for (int i = 0; i < n_in && i < 6; ++i) {
        const int s = in_sizes[i];
        const float* p = (const float*)d_in[i];
        if (s == 16384 * 256) feat[0] = p;
        else if (s == 16384 * 512) feat[1] = p;
        else if (s == 16384 * 1024) feat[2] = p;
        else if (s == 1024 * 256) memp[0] = p;
        else if (s == 1024 * 512) memp[1] = p;
        else if (s == 1024 * 1024) memp[2] = p;
    }
    float* out = (float*)d_out;
    short* nm0 = (short*)d_ws;
    short* nm1 = nm0 + 1024 * 256;
    short* nm2 = nm1 + 1024 * 512;

    // output layout (floats): out0 | out1 | out2 | w0 | w1 | w2
    const size_t O0 = 0;
    const size_t O1 = (size_t)16384 * 512;
    const size_t O2 = O1 + (size_t)16384 * 1024;
    const size_t W0 = O2 + (size_t)16384 * 2048;
    const size_t W1 = W0 + (size_t)16384 * 1024;
    const size_t W2 = W1 + (size_t)16384 * 1024;

    prep_all<<<192, 256, 0, stream>>>(memp[0], nm0, memp[1], nm1, memp[2], nm2);

    fused_all<<<1536, 512, 0, stream>>>(
        feat[0], memp[0], nm0, out + O0, out + W0,
        feat[1], memp[1], nm1, out + O1, out + W1,
        feat[2], memp[2], nm2, out + O2, out + W2);
}

// Round 6
// 277.833 us; speedup vs baseline: 1.2761x; 1.2761x over previous
//
#include <hip/hip_runtime.h>
#include <stdint.h>

typedef float f32x4 __attribute__((ext_vector_type(4)));
typedef short s16x8 __attribute__((ext_vector_type(8)));
typedef short s16x4 __attribute__((ext_vector_type(4)));

__device__ __forceinline__ unsigned short f2bf(float f) {
    uint32_t u = __float_as_uint(f);
    u += 0x7FFFu + ((u >> 16) & 1u);   // round-to-nearest-even
    return (unsigned short)(u >> 16);
}

// ---------- prep: normalize mem rows, emit MFMA-fragment-packed bf16 ----------
// packed tile (ct,kb): cols [ct*16..+15] x k [kb*32..+31] as 512 shorts at
// ((ct*(C/32)+kb)*512); short lane*8+j = B[col=ct*16+(lane&15)][k=kb*32+(lane>>4)*8+j]
template<int C>
__device__ __forceinline__ void prep_body(const float* __restrict__ mp,
                                          short* __restrict__ nmp,
                                          int ct, short* stage) {
    const int tid = threadIdx.x;       // 256 threads
    const int row = tid >> 4;          // 0..15 (B column)
    const int c4  = tid & 15;
    constexpr int IT = C / 64;
    const f32x4* src = (const f32x4*)(mp + (size_t)(ct * 16 + row) * C);
    f32x4 vals[IT];
    float ss = 0.f;
#pragma unroll
    for (int i = 0; i < IT; ++i) {
        f32x4 v = src[c4 + 16 * i];
        vals[i] = v;
        ss += v.x * v.x + v.y * v.y + v.z * v.z + v.w * v.w;
    }
#pragma unroll
    for (int m = 1; m < 16; m <<= 1) ss += __shfl_xor(ss, m);
    const float inv = 1.f / fmaxf(sqrtf(ss), 1e-12f);
#pragma unroll
    for (int i = 0; i < IT; ++i) {
        f32x4 v = vals[i];
        s16x4 o;
        o[0] = (short)f2bf(v.x * inv);
        o[1] = (short)f2bf(v.y * inv);
        o[2] = (short)f2bf(v.z * inv);
        o[3] = (short)f2bf(v.w * inv);
        *(s16x4*)&stage[row * C + (c4 + 16 * i) * 4] = o;
    }
    __syncthreads();
    const int lane = tid & 63;
    const int wv = tid >> 6;
    constexpr int NKB = C / 32;
#pragma unroll
    for (int j = 0; j < NKB / 4; ++j) {
        const int kb = j * 4 + wv;
        const s16x8 v = *(const s16x8*)&stage[(lane & 15) * C + kb * 32 + (lane >> 4) * 8];
        *(s16x8*)&nmp[((size_t)ct * NKB + kb) * 512 + lane * 8] = v;
    }
}

__global__ __launch_bounds__(256) void prep_all(const float* m0, short* n0,
                                                const float* m1, short* n1,
                                                const float* m2, short* n2) {
    __shared__ short stage[16 * 1024];
    const int bid = blockIdx.x;
    if (bid < 64) prep_body<256>(m0, n0, bid, stage);
    else if (bid < 128) prep_body<512>(m1, n1, bid - 64, stage);
    else prep_body<1024>(m2, n2, bid - 128, stage);
}

// ---------- fused unit body: pipelined KC=64 chunks, double-buffered LDS ----------
// All streaming traffic (f reads, f-copy/zero/W writes) is NONTEMPORAL so the
// packed-B nm array stays resident in each XCD's L2.
template<int C>
__device__ __forceinline__ void fused_body(const float* __restrict__ feat,
                                           const float* __restrict__ memv,
                                           const short* __restrict__ nm,
                                           float* __restrict__ out_cat,
                                           float* __restrict__ out_w,
                                           int tile, short* A_s, float (*red)[32],
                                           float* invn, int* rowflag, int* anyflag) {
    constexpr int KC = 64;                  // K chunk: LDS tile 32x64 bf16 = 4 KB
    constexpr int NCH = C / KC;             // 4 / 8 / 16
    constexpr int NKB = C / 32;
    const int tid = threadIdx.x;
    const int wave = tid >> 6;
    const int lane = tid & 63;
    const int g = lane >> 4;
    const int ml = lane & 15;
    const int row0 = tile * 32;
    const int prow = tid >> 4;              // fill row 0..31 (16 consecutive lanes/row)
    const int pc4 = tid & 15;               // float4 index within 64-float chunk row
    const int swzm = ml & 7;

    if (tid == 0) *anyflag = 0;

    f32x4 acc[2][8];
#pragma unroll
    for (int rt = 0; rt < 2; ++rt)
#pragma unroll
        for (int t = 0; t < 8; ++t)
            acc[rt][t] = (f32x4){0.f, 0.f, 0.f, 0.f};

    const f32x4* srcB = (const f32x4*)(feat + (size_t)(row0 + prow) * C);
    f32x4* dstfB = (f32x4*)(out_cat + (size_t)(row0 + prow) * (2 * C) + C);
    f32x4* dstzB = (f32x4*)(out_cat + (size_t)(row0 + prow) * (2 * C));
    const f32x4 z4 = {0.f, 0.f, 0.f, 0.f};
    const int ldsWr = prow * 64 + (((pc4 >> 1) ^ (prow & 7)) * 8) + (pc4 & 1) * 4;

    float ss = 0.f;
    f32x4 cur = __builtin_nontemporal_load(&srcB[pc4]);   // prologue: chunk 0

#pragma unroll
    for (int ck = 0; ck < NCH; ++ck) {
        // (a) prefetch next chunk (hidden under this chunk's GEMM)
        f32x4 nxt;
        if (ck + 1 < NCH) nxt = __builtin_nontemporal_load(&srcB[(ck + 1) * 16 + pc4]);
        // (b) process cur: f-copy, mf zeros, sumsq, bf16 -> swizzled LDS buf[ck&1]
        __builtin_nontemporal_store(cur, &dstfB[ck * 16 + pc4]);
        __builtin_nontemporal_store(z4, &dstzB[ck * 16 + pc4]);
        ss += cur.x * cur.x + cur.y * cur.y + cur.z * cur.z + cur.w * cur.w;
        s16x4 o;
        o[0] = (short)f2bf(cur.x);
        o[1] = (short)f2bf(cur.y);
        o[2] = (short)f2bf(cur.z);
        o[3] = (short)f2bf(cur.w);
        *(s16x4*)&A_s[(ck & 1) * 2048 + ldsWr] = o;
        // (c) barrier: drain LDS only — global loads/stores stay in flight
        asm volatile("s_waitcnt lgkmcnt(0)" ::: "memory");
        __builtin_amdgcn_s_barrier();
        asm volatile("" ::: "memory");
        // (d) GEMM this chunk: A from LDS buf[ck&1], packed B from L2
        const short* As = &A_s[(ck & 1) * 2048];
#pragma unroll
        for (int ks = 0; ks < 2; ++ks) {
            const int kb = ck * 2 + ks;
            const s16x8 a0 = *(const s16x8*)&As[ml * 64 + ((((ks << 2) | g) ^ swzm) * 8)];
            const s16x8 a1 = *(const s16x8*)&As[(16 + ml) * 64 + ((((ks << 2) | g) ^ swzm) * 8)];
            const short* nb = nm + ((size_t)(wave * 8) * NKB + kb) * 512 + lane * 8;
#pragma unroll
            for (int t = 0; t < 8; ++t) {
                const s16x8 b = *(const s16x8*)(nb + (size_t)t * NKB * 512);
                acc[0][t] = __builtin_amdgcn_mfma_f32_16x16x32_bf16(a0, b, acc[0][t], 0, 0, 0);
                acc[1][t] = __builtin_amdgcn_mfma_f32_16x16x32_bf16(a1, b, acc[1][t], 0, 0, 0);
            }
        }
        cur = nxt;
    }

    // ---- invn (norm applied post-GEMM: S = R * invn_row) ----
#pragma unroll
    for (int m = 1; m < 16; m <<= 1) ss += __shfl_xor(ss, m);
    if (pc4 == 0) invn[prow] = 1.f / fmaxf(sqrtf(ss), 1e-12f);
    __syncthreads();

    // C/D layout: col = ml, row = 16*rt + 4*g + i
    float Tt[2][4], IL[2][4];

    // ---- exp (no max-sub: |S| <= 1) + row sum ----
#pragma unroll
    for (int rt = 0; rt < 2; ++rt)
#pragma unroll
        for (int i = 0; i < 4; ++i) {
            const float inv = invn[rt * 16 + g * 4 + i];
            float s = 0.f;
#pragma unroll
            for (int t = 0; t < 8; ++t) {
                const float e = __expf(acc[rt][t][i] * inv);
                acc[rt][t][i] = e;
                s += e;
            }
#pragma unroll
            for (int msk = 1; msk < 16; msk <<= 1) s += __shfl_xor(s, msk);
            if (ml == 0) red[wave][rt * 16 + g * 4 + i] = s;
        }
    __syncthreads();
#pragma unroll
    for (int rt = 0; rt < 2; ++rt)
#pragma unroll
        for (int i = 0; i < 4; ++i) {
            const int row = rt * 16 + g * 4 + i;
            float s = red[0][row];
#pragma unroll
            for (int ww = 1; ww < 8; ++ww) s += red[ww][row];
            Tt[rt][i] = s;
        }

    // ---- softmax weight, hard-shrink, row L1 (disjoint red half: no barrier) ----
#pragma unroll
    for (int rt = 0; rt < 2; ++rt)
#pragma unroll
        for (int i = 0; i < 4; ++i) {
            const float tinv = 1.f / Tt[rt][i];
            float l1 = 0.f;
#pragma unroll
            for (int t = 0; t < 8; ++t) {
                const float w = acc[rt][t][i] * tinv;
                const float d = w - 0.0025f;
                const float v = (d > 0.f) ? (d * w / (d + 1e-12f)) : 0.f;
                acc[rt][t][i] = v;
                l1 += v;
            }
#pragma unroll
            for (int msk = 1; msk < 16; msk <<= 1) l1 += __shfl_xor(l1, msk);
            if (ml == 0) red[8 + wave][rt * 16 + g * 4 + i] = l1;
        }
    __syncthreads();
#pragma unroll
    for (int rt = 0; rt < 2; ++rt)
#pragma unroll
        for (int i = 0; i < 4; ++i) {
            const int row = rt * 16 + g * 4 + i;
            float l1 = red[8][row];
#pragma unroll
            for (int ww = 1; ww < 8; ++ww) l1 += red[8 + ww][row];
            IL[rt][i] = 1.f / fmaxf(l1, 1e-12f);
            if (wave == 0 && ml == 0) {
                rowflag[row] = (l1 > 0.f) ? 1 : 0;
                if (l1 > 0.f) *anyflag = 1;
            }
        }

    // ---- store W (nontemporal) ----
#pragma unroll
    for (int rt = 0; rt < 2; ++rt)
#pragma unroll
        for (int t = 0; t < 8; ++t) {
            const int col = wave * 128 + t * 16 + ml;
#pragma unroll
            for (int i = 0; i < 4; ++i) {
                __builtin_nontemporal_store(
                    acc[rt][t][i] * IL[rt][i],
                    &out_w[(size_t)(row0 + rt * 16 + g * 4 + i) * 1024 + col]);
            }
        }
    __threadfence_block();
    __syncthreads();

    // ---- mf fixup: only rows surviving the shrink (zeros already written) ----
    if (*anyflag != 0) {
        constexpr int CC = C / 64;
#pragma unroll
        for (int rr = 0; rr < 4; ++rr) {
            const int row = wave * 4 + rr;
            if (!rowflag[row]) continue;
            float* dst = out_cat + (size_t)(row0 + row) * (2 * C);
            float mfacc[CC];
#pragma unroll
            for (int cc = 0; cc < CC; ++cc) mfacc[cc] = 0.f;
            const float* wrow = out_w + (size_t)(row0 + row) * 1024;
            for (int jb = 0; jb < 1024; jb += 64) {
                const float wv = wrow[jb + lane];
                unsigned long long msk = __ballot(wv != 0.f);
                while (msk) {
                    const int j = __builtin_ctzll(msk);
                    msk &= msk - 1;
                    const float val = __shfl(wv, j);
                    const float* mrow = memv + (size_t)(jb + j) * C;
#pragma unroll
                    for (int cc = 0; cc < CC; ++cc)
                        mfacc[cc] += val * mrow[cc * 64 + lane];
                }
            }
#pragma unroll
            for (int cc = 0; cc < CC; ++cc) dst[cc * 64 + lane] = mfacc[cc];
        }
    }
}

// ---------- mega kernel: unit-sorted block order (one unit active at a time,
// so that unit's packed nm stays hot in every XCD's L2) ----------
__global__ __launch_bounds__(512, 4) void fused_all(
        const float* f0, const float* m0, const short* n0, float* o0, float* w0,
        const float* f1, const float* m1, const short* n1, float* o1, float* w1,
        const float* f2, const float* m2, const short* n2, float* o2, float* w2) {
    __shared__ short A_s[2 * 32 * 64];      // double-buffered 4 KB tiles
    __shared__ float red[16][32];
    __shared__ float invn[32];
    __shared__ int rowflag[32];
    __shared__ int anyflag;

    const int bid = blockIdx.x;
    if (bid < 512)
        fused_body<1024>(f2, m2, n2, o2, w2, bid, A_s, red, invn, rowflag, &anyflag);
    else if (bid < 1024)
        fused_body<512>(f1, m1, n1, o1, w1, bid - 512, A_s, red, invn, rowflag, &anyflag);
    else
        fused_body<256>(f0, m0, n0, o0, w0, bid - 1024, A_s, red, invn, rowflag, &anyflag);
}

extern "C" void kernel_launch(void* const* d_in, const int* in_sizes, int n_in,
                              void* d_out, int out_size, void* d_ws, size_t ws_size,
                              hipStream_t stream) {
    const float* feat[3] = {nullptr, nullptr, nullptr};
    const float* memp[3] = {nullptr, nullptr, nullptr};
    for (int i = 0; i < n_in && i < 6; ++i) {
        const int s = in_sizes[i];
        const float* p = (const float*)d_in[i];
        if (s == 16384 * 256) feat[0] = p;
        else if (s == 16384 * 512) feat[1] = p;
        else if (s == 16384 * 1024) feat[2] = p;
        else if (s == 1024 * 256) memp[0] = p;
        else if (s == 1024 * 512) memp[1] = p;
        else if (s == 1024 * 1024) memp[2] = p;
    }
    float* out = (float*)d_out;
    short* nm0 = (short*)d_ws;
    short* nm1 = nm0 + 1024 * 256;
    short* nm2 = nm1 + 1024 * 512;

    // output layout (floats): out0 | out1 | out2 | w0 | w1 | w2
    const size_t O0 = 0;
    const size_t O1 = (size_t)16384 * 512;
    const size_t O2 = O1 + (size_t)16384 * 1024;
    const size_t W0 = O2 + (size_t)16384 * 2048;
    const size_t W1 = W0 + (size_t)16384 * 1024;
    const size_t W2 = W1 + (size_t)16384 * 1024;

    prep_all<<<192, 256, 0, stream>>>(memp[0], nm0, memp[1], nm1, memp[2], nm2);

    fused_all<<<1536, 512, 0, stream>>>(
        feat[0], memp[0], nm0, out + O0, out + W0,
        feat[1], memp[1], nm1, out + O1, out + W1,
        feat[2], memp[2], nm2, out + O2, out + W2);
}